// Round 1
// baseline (994.678 us; speedup 1.0000x reference)
//
#include <hip/hip_runtime.h>

// RecursiveLSTM: B=1024 independent sequences, T=96, H=50, num_pred=12.
// One block per batch element; 1152 serial LSTM steps inside the kernel.
// Thread j<200 owns gate j. W_hh row held in 13 NAMED float4 registers
// (named SSA values, not an array -> cannot be demoted to scratch; the
// previous float w[52] version ran at VGPR_Count=36 => scratch-resident,
// re-loading 52 dwords/thread/step).

#define HSZ   50
#define G4    200      // 4*H gates
#define TLEN  96
#define MAXP  16       // >= num_pred

__global__ __launch_bounds__(256, 4)
void rec_lstm_kernel(const float* __restrict__ x,
                     const float* __restrict__ W_ih,
                     const float* __restrict__ W_hh,
                     const float* __restrict__ b_ih,
                     const float* __restrict__ b_hh,
                     const float* __restrict__ W_fc,
                     const float* __restrict__ b_fc,
                     const int*   __restrict__ num_pred,
                     float*       __restrict__ out)
{
    const int b   = blockIdx.x;
    const int tid = threadIdx.x;

    __shared__ float x_lds[TLEN];
    __shared__ float preds[MAXP];
    __shared__ __align__(16) float h_lds[52];   // padded to 13 float4
    __shared__ float gates[G4];

    // ---- one-time preload (all threads load; clamp row for tid>=200) ----
    const int    gid = (tid < G4) ? tid : 0;
    const float* wr  = W_hh + gid * HSZ;

    // 13 named float4 registers holding the W_hh row (pads = 0).
#define WLOAD(K) const float4 w##K = {wr[4*K+0], wr[4*K+1], wr[4*K+2], wr[4*K+3]};
    WLOAD(0) WLOAD(1) WLOAD(2) WLOAD(3) WLOAD(4) WLOAD(5)
    WLOAD(6) WLOAD(7) WLOAD(8) WLOAD(9) WLOAD(10) WLOAD(11)
    const float4 w12 = {wr[48], wr[49], 0.f, 0.f};
#undef WLOAD

    const float wih   = W_ih[gid];
    const float bsum  = b_ih[gid] + b_hh[gid];
    // unified activation: a = 1 - n/(exp(n*x)+1); n=1 -> sigmoid, n=2 -> tanh
    const float act_n = (tid >= 100 && tid < 150) ? 2.0f : 1.0f;

    const float wfc = (tid < HSZ) ? W_fc[tid] : 0.f;
    if (tid < TLEN) x_lds[tid] = x[b * TLEN + tid];
    if (tid == 0) { h_lds[50] = 0.f; h_lds[51] = 0.f; }
    const float bfc = b_fc[0];
    const int   NP  = num_pred[0];

    float c = 0.f;   // cell state, valid in threads < 50

    for (int p = 0; p < NP; ++p) {
        if (tid < HSZ) { c = 0.f; h_lds[tid] = 0.f; }
        __syncthreads();

        for (int t = 0; t < TLEN; ++t) {
            const int idx = p + t;                       // sliding window
            const float xv = (idx < TLEN) ? x_lds[idx] : preds[idx - TLEN];

            // ---- gate dot-product: 4 independent accumulator chains ----
            float a0 = fmaf(wih, xv, bsum);
            float a1 = 0.f, a2 = 0.f, a3 = 0.f;
            const float4* h4 = (const float4*)h_lds;     // broadcast reads
#define ACC(K) { const float4 hv = h4[K];                              \
                 a0 = fmaf(w##K.x, hv.x, a0);                          \
                 a1 = fmaf(w##K.y, hv.y, a1);                          \
                 a2 = fmaf(w##K.z, hv.z, a2);                          \
                 a3 = fmaf(w##K.w, hv.w, a3); }
            ACC(0) ACC(1) ACC(2) ACC(3) ACC(4) ACC(5) ACC(6)
            ACC(7) ACC(8) ACC(9) ACC(10) ACC(11) ACC(12)
#undef ACC
            const float acc = (a0 + a1) + (a2 + a3);

            // branch-free activation (no divergent dual-path in waves 1,2)
            const float e = __expf(act_n * acc);
            const float a = 1.0f - act_n / (e + 1.0f);

            if (tid < G4) gates[tid] = a;
            __syncthreads();

            if (tid < HSZ) {
                const float gi = gates[tid];
                const float gf = gates[tid + 50];
                const float gg = gates[tid + 100];
                const float go = gates[tid + 150];
                c = fmaf(gf, c, gi * gg);
                // tanh(c) = 1 - 2/(exp(2c)+1), inf-safe
                h_lds[tid] = go * (1.0f - 2.0f / (__expf(2.0f * c) + 1.0f));
            }
            __syncthreads();
        }

        // ---- FC head: pred = h . W_fc + b_fc (wave-0 reduction) ----
        float v = (tid < HSZ) ? h_lds[tid] * wfc : 0.f;
        if (tid < 64) {
            #pragma unroll
            for (int off = 32; off >= 1; off >>= 1)
                v += __shfl_down(v, off, 64);
            if (tid == 0) {
                const float pr = v + bfc;
                preds[p] = pr;
                out[b * NP + p] = pr;
            }
        }
        __syncthreads();   // preds visible before next pass reads it
    }
}

extern "C" void kernel_launch(void* const* d_in, const int* in_sizes, int n_in,
                              void* d_out, int out_size, void* d_ws, size_t ws_size,
                              hipStream_t stream)
{
    const float* x    = (const float*)d_in[0];
    const float* W_ih = (const float*)d_in[1];
    const float* W_hh = (const float*)d_in[2];
    const float* b_ih = (const float*)d_in[3];
    const float* b_hh = (const float*)d_in[4];
    const float* W_fc = (const float*)d_in[5];
    const float* b_fc = (const float*)d_in[6];
    const int*   np   = (const int*)d_in[7];
    float* out = (float*)d_out;

    const int B = in_sizes[0] / TLEN;   // 1024
    rec_lstm_kernel<<<B, 256, 0, stream>>>(x, W_ih, W_hh, b_ih, b_hh,
                                           W_fc, b_fc, np, out);
}

// Round 2
// 864.417 us; speedup vs baseline: 1.1507x; 1.1507x over previous
//
#include <hip/hip_runtime.h>

// RecursiveLSTM: B=1024 sequences, T=96, H=50, num_pred=12.
// WAVE-PER-SEQUENCE decomposition: 1024 blocks x 64 threads (one wave).
// Lane j<50 owns hidden unit j and computes ALL FOUR of its gates
// (i,f,g,o) = 4 dot-products over h, then c_j, h_j in-thread.
//  - zero gate communication (previous layout moved 200 gates through LDS
//    + 2 s_barrier across 4 waves EVERY step)
//  - per-step cross-lane traffic: 13 ds_read_b128 h-broadcasts + 1 ds_write
//  - single-wave block => __syncthreads() is near-free
// Weights: 4x50 = 200 floats in NAMED float4 registers. __launch_bounds__(64,1)
// gives a 512-VGPR budget so the allocator has no reason to spill them
// (round-1 failure: cap 128 under (256,4) => all weights spilled, VGPR=48).

#define HSZ   50
#define TLEN  96
#define MAXP  16

__global__ __launch_bounds__(64, 1)
void rec_lstm_kernel(const float* __restrict__ x,
                     const float* __restrict__ W_ih,
                     const float* __restrict__ W_hh,
                     const float* __restrict__ b_ih,
                     const float* __restrict__ b_hh,
                     const float* __restrict__ W_fc,
                     const float* __restrict__ b_fc,
                     const int*   __restrict__ num_pred,
                     float*       __restrict__ out)
{
    const int b = blockIdx.x;
    const int j = threadIdx.x;            // hidden-unit index; active j<50
    const int u = (j < HSZ) ? j : 0;      // clamped row for idle lanes

    __shared__ float x_lds[TLEN];
    __shared__ float preds[MAXP];
    __shared__ __align__(16) float h_lds[52];   // padded to 13 float4

    // ---- one-time preload: W_hh rows for the 4 gates of unit u ----
    const float* ri = W_hh + (u +   0) * HSZ;
    const float* rf = W_hh + (u +  50) * HSZ;
    const float* rg = W_hh + (u + 100) * HSZ;
    const float* ro = W_hh + (u + 150) * HSZ;

#define LD4(P,K)  {(P)[4*(K)], (P)[4*(K)+1], (P)[4*(K)+2], (P)[4*(K)+3]}
#define LDROW(N,P) \
    const float4 N##0=LD4(P,0),  N##1=LD4(P,1),  N##2=LD4(P,2),  N##3=LD4(P,3),  \
                 N##4=LD4(P,4),  N##5=LD4(P,5),  N##6=LD4(P,6),  N##7=LD4(P,7),  \
                 N##8=LD4(P,8),  N##9=LD4(P,9),  N##10=LD4(P,10), N##11=LD4(P,11); \
    const float4 N##12 = {(P)[48], (P)[49], 0.f, 0.f};
    LDROW(wi, ri)
    LDROW(wf, rf)
    LDROW(wg, rg)
    LDROW(wo, ro)
#undef LDROW
#undef LD4

    const float xii = W_ih[u], xif = W_ih[u+50], xig = W_ih[u+100], xio = W_ih[u+150];
    const float bi = b_ih[u]     + b_hh[u];
    const float bf = b_ih[u+50]  + b_hh[u+50];
    const float bg = b_ih[u+100] + b_hh[u+100];
    const float bo = b_ih[u+150] + b_hh[u+150];
    const float wfc = (j < HSZ) ? W_fc[j] : 0.f;
    const float bfc = b_fc[0];
    const int   NP  = num_pred[0];

    if (j < 48) { x_lds[j] = x[b*TLEN + j]; x_lds[j+48] = x[b*TLEN + j + 48]; }
    if (j == 0) { h_lds[50] = 0.f; h_lds[51] = 0.f; }

    float c = 0.f;   // cell state of unit j

    for (int p = 0; p < NP; ++p) {
        if (j < HSZ) { c = 0.f; h_lds[j] = 0.f; }
        __syncthreads();

        float hn = 0.f;   // h_j, kept in-register for the FC head

        for (int t = 0; t < TLEN; ++t) {
            const int idx = p + t;                        // sliding window
            const float xv = (idx < TLEN) ? x_lds[idx] : preds[idx - TLEN];

            // ---- 4 gate dot-products, 4 independent FMA chains ----
            float ai = fmaf(xii, xv, bi);
            float af = fmaf(xif, xv, bf);
            float ag = fmaf(xig, xv, bg);
            float ao = fmaf(xio, xv, bo);
            const float4* h4 = (const float4*)h_lds;      // broadcast reads
#define ACC(K) { const float4 hv = h4[K];                                  \
    ai = fmaf(wi##K.x, hv.x, ai); af = fmaf(wf##K.x, hv.x, af);            \
    ag = fmaf(wg##K.x, hv.x, ag); ao = fmaf(wo##K.x, hv.x, ao);            \
    ai = fmaf(wi##K.y, hv.y, ai); af = fmaf(wf##K.y, hv.y, af);            \
    ag = fmaf(wg##K.y, hv.y, ag); ao = fmaf(wo##K.y, hv.y, ao);            \
    ai = fmaf(wi##K.z, hv.z, ai); af = fmaf(wf##K.z, hv.z, af);            \
    ag = fmaf(wg##K.z, hv.z, ag); ao = fmaf(wo##K.z, hv.z, ao);            \
    ai = fmaf(wi##K.w, hv.w, ai); af = fmaf(wf##K.w, hv.w, af);            \
    ag = fmaf(wg##K.w, hv.w, ag); ao = fmaf(wo##K.w, hv.w, ao); }
            ACC(0) ACC(1) ACC(2) ACC(3) ACC(4) ACC(5) ACC(6)
            ACC(7) ACC(8) ACC(9) ACC(10) ACC(11) ACC(12)
#undef ACC

            // activations: sigmoid(i,f,o), tanh(g); inf-safe forms
            const float gi = 1.0f / (1.0f + __expf(-ai));
            const float gf = 1.0f / (1.0f + __expf(-af));
            const float gg = 1.0f - 2.0f / (__expf(2.0f * ag) + 1.0f);
            const float go = 1.0f / (1.0f + __expf(-ao));

            c  = fmaf(gf, c, gi * gg);
            hn = go * (1.0f - 2.0f / (__expf(2.0f * c) + 1.0f));

            if (j < HSZ) h_lds[j] = hn;
            __syncthreads();   // single wave: near-free; orders write->reads
        }

        // ---- FC head: pred = h . W_fc + b_fc (full-wave shuffle reduce) ----
        float v = (j < HSZ) ? hn * wfc : 0.f;
        #pragma unroll
        for (int off = 32; off >= 1; off >>= 1)
            v += __shfl_down(v, off, 64);
        if (j == 0) {
            const float pr = v + bfc;
            preds[p] = pr;
            out[b * NP + p] = pr;
        }
        __syncthreads();   // preds visible before next pass reads it
    }
}

extern "C" void kernel_launch(void* const* d_in, const int* in_sizes, int n_in,
                              void* d_out, int out_size, void* d_ws, size_t ws_size,
                              hipStream_t stream)
{
    const float* x    = (const float*)d_in[0];
    const float* W_ih = (const float*)d_in[1];
    const float* W_hh = (const float*)d_in[2];
    const float* b_ih = (const float*)d_in[3];
    const float* b_hh = (const float*)d_in[4];
    const float* W_fc = (const float*)d_in[5];
    const float* b_fc = (const float*)d_in[6];
    const int*   np   = (const int*)d_in[7];
    float* out = (float*)d_out;

    const int B = in_sizes[0] / TLEN;   // 1024
    rec_lstm_kernel<<<B, 64, 0, stream>>>(x, W_ih, W_hh, b_ih, b_hh,
                                          W_fc, b_fc, np, out);
}